// Round 12
// baseline (57.477 us; speedup 1.0000x reference)
//
#include <hip/hip_runtime.h>

#define HH 160
#define WW 160
#define CC 32
#define NN 8
#define PIX (HH * WW)   // 25600
#define COLS 168        // LDS feature row stride (162 cols used: w=-1..160)

typedef float f32x2 __attribute__((ext_vector_type(2)));

// R6 structure (proven best: full-row write-coherent 640-thr block, kv[36]
// resident in VGPRs) + LDS-staged halo-padded feature rows. Taps become LDS
// reads (no 3x redundant global loads, no boundary branches). 16 channels
// staged per half-pass: ft_lds 32 KB + kv_lds 23 KB = 55 KB -> 2 blocks/CU.
__global__ __launch_bounds__(640) void pixelconv_k(
    const float* __restrict__ feature,   // [8,32,160,160]
    const float* __restrict__ kern,      // [8,36,160,160]
    float* __restrict__ out)             // [8,32,320,320]
{
    const int bx = blockIdx.x;                 // 0..159
    const int h  = (bx & 7) * 20 + (bx >> 3);  // XCD-chunked h swizzle
    const int n  = blockIdx.y;                 // 0..7
    const int t  = threadIdx.x;                // 0..639
    const int wl = t % 160;                    // w position
    const int cg = t / 160;                    // 0..3

    __shared__ float kv_lds[36 * 160];         // 23040 B
    __shared__ float ft_lds[48 * COLS];        // 16 ch x 3 rows, 32256 B

    // ---- stage kernel[n][0:36][h][0:160] into LDS (9 iters, coalesced) ----
    const float* kbase = kern + (size_t)n * 36 * PIX + (size_t)h * WW;
    #pragma unroll
    for (int r = 0; r < 9; ++r) {
        const int idx = t + r * 640;           // 5760 = 9*640 exactly
        const int j   = idx / 160;
        const int ws  = idx - j * 160;
        kv_lds[idx] = kbase[(size_t)j * PIX + ws];
    }

    float kv[36];
    const bool kvload[1] = {};
    (void)kvload;

    #pragma unroll 1
    for (int half = 0; half < 2; ++half) {
        const int c0 = half * 16;

        // ---- stage 16 channels x 3 halo rows x 162 cols into LDS ----
        const float* fb = feature + ((size_t)(n * CC + c0)) * PIX;
        #pragma unroll
        for (int it = 0; it < 13; ++it) {
            const int idx = t + it * 640;
            if (idx < 48 * 162) {
                const int row = idx / 162;      // row = ch*3 + dy
                const int col = idx - row * 162;
                const int ch  = row / 3;
                const int dy  = row - ch * 3;
                const int hh  = h + dy - 1;
                const int w   = col - 1;
                float v = 0.f;
                if ((unsigned)hh < HH && (unsigned)w < WW)
                    v = fb[(size_t)ch * PIX + (size_t)hh * WW + w];
                ft_lds[row * COLS + col] = v;
            }
        }
        __syncthreads();

        // kv regs: read once (after the first barrier makes kv_lds visible)
        if (half == 0) {
            #pragma unroll
            for (int j = 0; j < 36; ++j) kv[j] = kv_lds[j * 160 + wl];
        }

        // ---- compute this thread's 4 channels of the half ----
        float* oc = out + ((size_t)(n * CC + c0 + cg * 4)) * 4 * PIX
                        + (size_t)(2 * h) * (2 * WW) + 2 * wl;

        #pragma unroll 2
        for (int i = 0; i < 4; ++i) {
            const int chl = cg * 4 + i;         // 0..15 within half
            const float* fr = &ft_lds[(chl * 3) * COLS + wl];  // col wl = w-1

            // taps: r{dy}[dx] = feature[h+dy-1][w+dx-1], dx,dy in 0..2
            float r0[3], r1[3], r2[3];
            #pragma unroll
            for (int j = 0; j < 3; ++j) {
                r0[j] = fr[j];
                r1[j] = fr[COLS + j];
                r2[j] = fr[2 * COLS + j];
            }

            float a0 = 0.f, a1 = 0.f, a2 = 0.f, a3 = 0.f;
            #pragma unroll
            for (int dx = 0; dx < 3; ++dx) {
                #pragma unroll
                for (int dy = 0; dy < 3; ++dy) {
                    const int k = dx * 3 + dy;
                    const float f = (dy == 0) ? r0[dx] : (dy == 1) ? r1[dx] : r2[dx];
                    a0 = fmaf(f, kv[4 * k + 0], a0);
                    a1 = fmaf(f, kv[4 * k + 1], a1);
                    a2 = fmaf(f, kv[4 * k + 2], a2);
                    a3 = fmaf(f, kv[4 * k + 3], a3);
                }
            }

            // pixel shuffle: s = r1*2 + r2 -> rows 2h (+0) and 2h+1 (+320)
            *(f32x2*)(oc)          = (f32x2){a0, a1};
            *(f32x2*)(oc + 2 * WW) = (f32x2){a2, a3};
            oc += (size_t)4 * PIX;              // next channel's plane
        }
        __syncthreads();   // before next half overwrites ft_lds
    }
}

extern "C" void kernel_launch(void* const* d_in, const int* in_sizes, int n_in,
                              void* d_out, int out_size, void* d_ws, size_t ws_size,
                              hipStream_t stream) {
    const float* feature = (const float*)d_in[0];
    const float* kern    = (const float*)d_in[1];
    float* out           = (float*)d_out;

    dim3 grid(HH, NN, 1);   // (160, 8)
    pixelconv_k<<<grid, 640, 0, stream>>>(feature, kern, out);
}

// Round 13
// 34.789 us; speedup vs baseline: 1.6522x; 1.6522x over previous
//
#include <hip/hip_runtime.h>

#define HH 160
#define WW 160
#define CC 32
#define NN 8
#define PIX (HH * WW)   // 25600

typedef float f32x2 __attribute__((ext_vector_type(2)));
typedef float f32x2u __attribute__((ext_vector_type(2), aligned(4)));

// R6 structure EXACTLY (proven best 32.3us: 640-thr full-row write-coherent
// block, XCD-swizzled h, kv[36] resident via LDS->VGPR, f32x2 stores), with
// ONE change: per channel-row the 3-tap window is fetched with an unaligned
// f32x2 + a scalar (2 VMEM insts) instead of 3 scalar loads. Edge lanes
// (w==0 / w==159) shift the window so all loads stay inside the row; taps
// are picked out with cndmask selects. Cuts tap VMEM insts 72->48/thread
// and removes ~40% of redundant L1 tap bytes.
__global__ __launch_bounds__(640) void pixelconv_k(
    const float* __restrict__ feature,   // [8,32,160,160]
    const float* __restrict__ kern,      // [8,36,160,160]
    float* __restrict__ out)             // [8,32,320,320]
{
    const int bx = blockIdx.x;                 // 0..159
    const int h  = (bx & 7) * 20 + (bx >> 3);  // XCD-chunked h swizzle
    const int n  = blockIdx.y;                 // 0..7
    const int t  = threadIdx.x;                // 0..639
    const int wl = t % 160;                    // w position
    const int cg = t / 160;                    // 0..3 channel group (8 ch)

    // ---- stage kernel[n][0:36][h][0:160] into LDS (9 iters, coalesced) ----
    __shared__ float kv_lds[36 * 160];
    const float* kbase = kern + (size_t)n * 36 * PIX + (size_t)h * WW;
    #pragma unroll
    for (int r = 0; r < 9; ++r) {
        const int idx = t + r * 640;           // 5760 = 9 * 640 exactly
        const int j   = idx / 160;
        const int ws  = idx - j * 160;
        kv_lds[idx] = kbase[(size_t)j * PIX + ws];
    }
    __syncthreads();

    // per-thread copy of the 36 taps for its pixel (bank-conflict-free)
    float kv[36];
    #pragma unroll
    for (int j = 0; j < 36; ++j) kv[j] = kv_lds[j * 160 + wl];

    const bool hm = (h > 0), hp = (h < HH - 1);
    const bool wz0 = (wl == 0), wz159 = (wl == 159);
    // window shift: loads always within [row, row+159]
    const int off = wz0 ? 0 : (wz159 ? -2 : -1);

    const float* fc = feature + ((size_t)(n * CC + cg * 8)) * PIX
                              + (size_t)h * WW + wl + off;
    float* oc = out + ((size_t)(n * CC + cg * 8)) * 4 * PIX
                    + (size_t)(2 * h) * (2 * WW) + 2 * wl;

    #pragma unroll 2
    for (int i = 0; i < 8; ++i) {
        // taps per row dy: l=w-1, m=w, r=w+1 via f32x2u + scalar
        float lft[3], mid[3], rgt[3];
        #pragma unroll
        for (int dy = 0; dy < 3; ++dy) {
            const bool okh = (dy == 1) || (dy == 0 ? hm : hp);
            const float* p = fc + (dy - 1) * WW;
            f32x2 v2 = okh ? (f32x2)(*(const f32x2u*)p) : (f32x2){0.f, 0.f};
            float  s  = okh ? p[2] : 0.f;
            lft[dy] = wz0 ? 0.f : (wz159 ? v2.y : v2.x);
            mid[dy] = wz0 ? v2.x : (wz159 ? s : v2.y);
            rgt[dy] = wz159 ? 0.f : (wz0 ? v2.y : s);
        }

        float a0 = 0.f, a1 = 0.f, a2 = 0.f, a3 = 0.f;
        #pragma unroll
        for (int dx = 0; dx < 3; ++dx) {
            #pragma unroll
            for (int dy = 0; dy < 3; ++dy) {
                const int k = dx * 3 + dy;
                const float f = (dx == 0) ? lft[dy] : (dx == 1) ? mid[dy] : rgt[dy];
                a0 = fmaf(f, kv[4 * k + 0], a0);
                a1 = fmaf(f, kv[4 * k + 1], a1);
                a2 = fmaf(f, kv[4 * k + 2], a2);
                a3 = fmaf(f, kv[4 * k + 3], a3);
            }
        }

        // pixel shuffle: s = r1*2 + r2 -> rows 2h (offset 0) and 2h+1 (+320)
        *(f32x2*)(oc)          = (f32x2){a0, a1};
        *(f32x2*)(oc + 2 * WW) = (f32x2){a2, a3};

        fc += PIX;               // next channel's feature plane
        oc += (size_t)4 * PIX;   // next channel's output plane
    }
}

extern "C" void kernel_launch(void* const* d_in, const int* in_sizes, int n_in,
                              void* d_out, int out_size, void* d_ws, size_t ws_size,
                              hipStream_t stream) {
    const float* feature = (const float*)d_in[0];
    const float* kern    = (const float*)d_in[1];
    float* out           = (float*)d_out;

    dim3 grid(HH, NN, 1);   // (160, 8)
    pixelconv_k<<<grid, 640, 0, stream>>>(feature, kern, out);
}

// Round 14
// 31.739 us; speedup vs baseline: 1.8109x; 1.0961x over previous
//
#include <hip/hip_runtime.h>

#define HH 160
#define WW 160
#define CC 32
#define NN 8
#define PIX (HH * WW)   // 25600

typedef float f32x2 __attribute__((ext_vector_type(2)));

// R6's per-thread code EXACTLY (proven best: kv[36] resident via LDS->VGPR,
// 3 scalar taps/row from global (L1-served), f32x2 stores, full-row write
// coherence) -- but with 320-thread blocks (2 cg x 160 w, 16 channels per
// block) instead of 640. At ~72 VGPR the 16-wave/CU cap fits THREE resident
// 5-wave blocks (15 waves/CU) vs R6's single 10-wave block -> 1.5x TLP to
// overlap VMEM issue with the HBM stream. Grid (160 h, 2 channel-half, 8 n).
__global__ __launch_bounds__(320) void pixelconv_k(
    const float* __restrict__ feature,   // [8,32,160,160]
    const float* __restrict__ kern,      // [8,36,160,160]
    float* __restrict__ out)             // [8,32,320,320]
{
    const int bx = blockIdx.x;                 // 0..159
    const int h  = (bx & 7) * 20 + (bx >> 3);  // XCD-chunked h swizzle
    const int chalf = blockIdx.y;              // 0..1 (16 channels each)
    const int n  = blockIdx.z;                 // 0..7
    const int t  = threadIdx.x;                // 0..319
    const int wl = t % 160;                    // w position
    const int cg = t / 160;                    // 0..1 channel group (8 ch)

    // ---- stage kernel[n][0:36][h][0:160] into LDS (18 iters, coalesced) ----
    __shared__ float kv_lds[36 * 160];
    const float* kbase = kern + (size_t)n * 36 * PIX + (size_t)h * WW;
    #pragma unroll
    for (int r = 0; r < 18; ++r) {
        const int idx = t + r * 320;           // 5760 = 18 * 320 exactly
        const int j   = idx / 160;
        const int ws  = idx - j * 160;
        kv_lds[idx] = kbase[(size_t)j * PIX + ws];
    }
    __syncthreads();

    // per-thread copy of the 36 taps for its pixel (bank-conflict-free)
    float kv[36];
    #pragma unroll
    for (int j = 0; j < 36; ++j) kv[j] = kv_lds[j * 160 + wl];

    const bool hm = (h > 0), hp = (h < HH - 1);
    const bool wm = (wl > 0), wp = (wl < WW - 1);

    const int cbase = chalf * 16 + cg * 8;
    const float* fc = feature + ((size_t)(n * CC + cbase)) * PIX
                              + (size_t)h * WW + wl;
    float* oc = out + ((size_t)(n * CC + cbase)) * 4 * PIX
                    + (size_t)(2 * h) * (2 * WW) + 2 * wl;

    #pragma unroll 2
    for (int i = 0; i < 8; ++i) {
        // 9 taps, k = dx*3 + dy -> feature[h+dy-1][w+dx-1], imm offsets
        float f[9];
        #pragma unroll
        for (int dx = 0; dx < 3; ++dx) {
            #pragma unroll
            for (int dy = 0; dy < 3; ++dy) {
                const bool ok = (dy != 0 || hm) && (dy != 2 || hp) &&
                                (dx != 0 || wm) && (dx != 2 || wp);
                f[dx * 3 + dy] = ok ? fc[(dy - 1) * WW + (dx - 1)] : 0.0f;
            }
        }

        float a0 = 0.f, a1 = 0.f, a2 = 0.f, a3 = 0.f;
        #pragma unroll
        for (int k = 0; k < 9; ++k) {
            a0 = fmaf(f[k], kv[4 * k + 0], a0);
            a1 = fmaf(f[k], kv[4 * k + 1], a1);
            a2 = fmaf(f[k], kv[4 * k + 2], a2);
            a3 = fmaf(f[k], kv[4 * k + 3], a3);
        }

        // pixel shuffle: s = r1*2 + r2 -> rows 2h (offset 0) and 2h+1 (+320)
        *(f32x2*)(oc)          = (f32x2){a0, a1};
        *(f32x2*)(oc + 2 * WW) = (f32x2){a2, a3};

        fc += PIX;               // next channel's feature plane
        oc += (size_t)4 * PIX;   // next channel's output plane
    }
}

extern "C" void kernel_launch(void* const* d_in, const int* in_sizes, int n_in,
                              void* d_out, int out_size, void* d_ws, size_t ws_size,
                              hipStream_t stream) {
    const float* feature = (const float*)d_in[0];
    const float* kern    = (const float*)d_in[1];
    float* out           = (float*)d_out;

    dim3 grid(HH, 2, NN);   // (160 h, 2 channel-half, 8 n)
    pixelconv_k<<<grid, 320, 0, stream>>>(feature, kern, out);
}

// Round 15
// 31.643 us; speedup vs baseline: 1.8164x; 1.0030x over previous
//
#include <hip/hip_runtime.h>

#define HH 160
#define WW 160
#define CC 32
#define NN 8
#define PIX (HH * WW)   // 25600

typedef float f32x2 __attribute__((ext_vector_type(2)));

// R13 structure (proven best 31.7us: 320-thr blocks, full-row write
// coherence, XCD-swizzled h, kv[36] resident via LDS->VGPR, f32x2 stores)
// pushed to the 64-VGPR occupancy tier: __launch_bounds__(320,8) caps the
// allocator at 64 VGPR -> 8 waves/SIMD -> 6 resident blocks (30 waves/CU,
// 2x R13). Channel loop unroll=1 keeps the live set (kv36+f9+acc4+addr)
// under 64 so the cap is feasible without spill/remat.
__global__ __launch_bounds__(320, 8) void pixelconv_k(
    const float* __restrict__ feature,   // [8,32,160,160]
    const float* __restrict__ kern,      // [8,36,160,160]
    float* __restrict__ out)             // [8,32,320,320]
{
    const int bx = blockIdx.x;                 // 0..159
    const int h  = (bx & 7) * 20 + (bx >> 3);  // XCD-chunked h swizzle
    const int chalf = blockIdx.y;              // 0..1 (16 channels each)
    const int n  = blockIdx.z;                 // 0..7
    const int t  = threadIdx.x;                // 0..319
    const int wl = t % 160;                    // w position
    const int cg = t / 160;                    // 0..1 channel group (8 ch)

    // ---- stage kernel[n][0:36][h][0:160] into LDS (18 iters, coalesced) ----
    __shared__ float kv_lds[36 * 160];
    const float* kbase = kern + (size_t)n * 36 * PIX + (size_t)h * WW;
    #pragma unroll
    for (int r = 0; r < 18; ++r) {
        const int idx = t + r * 320;           // 5760 = 18 * 320 exactly
        const int j   = idx / 160;
        const int ws  = idx - j * 160;
        kv_lds[idx] = kbase[(size_t)j * PIX + ws];
    }
    __syncthreads();

    // per-thread copy of the 36 taps for its pixel (bank-conflict-free)
    float kv[36];
    #pragma unroll
    for (int j = 0; j < 36; ++j) kv[j] = kv_lds[j * 160 + wl];

    const bool hm = (h > 0), hp = (h < HH - 1);
    const bool wm = (wl > 0), wp = (wl < WW - 1);

    const int cbase = chalf * 16 + cg * 8;
    const float* fc = feature + ((size_t)(n * CC + cbase)) * PIX
                              + (size_t)h * WW + wl;
    float* oc = out + ((size_t)(n * CC + cbase)) * 4 * PIX
                    + (size_t)(2 * h) * (2 * WW) + 2 * wl;

    #pragma unroll 1
    for (int i = 0; i < 8; ++i) {
        // 9 taps, k = dx*3 + dy -> feature[h+dy-1][w+dx-1], imm offsets
        float f[9];
        #pragma unroll
        for (int dx = 0; dx < 3; ++dx) {
            #pragma unroll
            for (int dy = 0; dy < 3; ++dy) {
                const bool ok = (dy != 0 || hm) && (dy != 2 || hp) &&
                                (dx != 0 || wm) && (dx != 2 || wp);
                f[dx * 3 + dy] = ok ? fc[(dy - 1) * WW + (dx - 1)] : 0.0f;
            }
        }

        float a0 = 0.f, a1 = 0.f, a2 = 0.f, a3 = 0.f;
        #pragma unroll
        for (int k = 0; k < 9; ++k) {
            a0 = fmaf(f[k], kv[4 * k + 0], a0);
            a1 = fmaf(f[k], kv[4 * k + 1], a1);
            a2 = fmaf(f[k], kv[4 * k + 2], a2);
            a3 = fmaf(f[k], kv[4 * k + 3], a3);
        }

        // pixel shuffle: s = r1*2 + r2 -> rows 2h (offset 0) and 2h+1 (+320)
        *(f32x2*)(oc)          = (f32x2){a0, a1};
        *(f32x2*)(oc + 2 * WW) = (f32x2){a2, a3};

        fc += PIX;               // next channel's feature plane
        oc += (size_t)4 * PIX;   // next channel's output plane
    }
}

extern "C" void kernel_launch(void* const* d_in, const int* in_sizes, int n_in,
                              void* d_out, int out_size, void* d_ws, size_t ws_size,
                              hipStream_t stream) {
    const float* feature = (const float*)d_in[0];
    const float* kern    = (const float*)d_in[1];
    float* out           = (float*)d_out;

    dim3 grid(HH, 2, NN);   // (160 h, 2 channel-half, 8 n)
    pixelconv_k<<<grid, 320, 0, stream>>>(feature, kern, out);
}